// Round 1
// baseline (314.182 us; speedup 1.0000x reference)
//
#include <hip/hip_runtime.h>
#include <stdint.h>
#include <stddef.h>

#define SEQ 2048
#define NH 16
#define HD 64
#define NB 2
#define HID 1024

typedef short bf16x8 __attribute__((ext_vector_type(8)));
typedef float f32x4 __attribute__((ext_vector_type(4)));

__device__ __forceinline__ unsigned short f2bf(float f) {
  unsigned u = __float_as_uint(f);
  u += 0x7fffu + ((u >> 16) & 1u);
  return (unsigned short)(u >> 16);
}

__device__ __forceinline__ void load_lds16(const void* g, void* l) {
  __builtin_amdgcn_global_load_lds(
      (const __attribute__((address_space(1))) unsigned int*)g,
      (__attribute__((address_space(3))) unsigned int*)l, 16, 0, 0);
}

// ---------------- fp32 -> bf16 conversion of x and the 4 weight matrices ----
__global__ __launch_bounds__(256) void convert_all(
    const float* __restrict__ x, const float* __restrict__ wq,
    const float* __restrict__ wk, const float* __restrict__ wv,
    const float* __restrict__ wo, unsigned short* __restrict__ dst) {
  long i = ((long)blockIdx.x * 256 + threadIdx.x) * 4;
  const float* src; long off;
  if (i < 4194304L)      { src = x;  off = i; }
  else if (i < 5242880L) { src = wq; off = i - 4194304L; }
  else if (i < 6291456L) { src = wk; off = i - 5242880L; }
  else if (i < 7340032L) { src = wv; off = i - 6291456L; }
  else                   { src = wo; off = i - 7340032L; }
  float4 v = *reinterpret_cast<const float4*>(src + off);
  ushort4 o;
  o.x = f2bf(v.x); o.y = f2bf(v.y); o.z = f2bf(v.z); o.w = f2bf(v.w);
  *reinterpret_cast<ushort4*>(dst + i) = o;
}

// ---------------- mask -> 64x64-block "any zero" map ------------------------
__global__ __launch_bounds__(256) void mask_reduce(const int* __restrict__ mask,
                                                   int* __restrict__ map) {
  const int qb = blockIdx.y, kb = blockIdx.x;
  int bad = 0;
  for (int i = threadIdx.x; i < 4096; i += 256) {
    int qq = i >> 6, kk = i & 63;
    bad |= (mask[(size_t)(qb * 64 + qq) * SEQ + kb * 64 + kk] == 0);
  }
  __shared__ int red[4];
  unsigned long long any = __ballot(bad);
  if ((threadIdx.x & 63) == 0) red[threadIdx.x >> 6] = (any != 0ULL);
  __syncthreads();
  if (threadIdx.x == 0) map[qb * 32 + kb] = red[0] | red[1] | red[2] | red[3];
}

// ---------------- shared GEMM main loop: C(128x64) = A * B^T ----------------
// A: MxK row-major bf16 (K=HID), Bw: NxK row-major bf16. 128 threads (2 waves,
// each wave computes 64 rows x 64 cols as 4x4 MFMA 16x16x32 tiles).
__device__ __forceinline__ void gemm_bt_core(
    const unsigned short* __restrict__ A, const unsigned short* __restrict__ Bw,
    int m0, int n0, unsigned short* As, unsigned short* Bs, f32x4 acc[4][4]) {
  const int t = threadIdx.x;
  const int lane = t & 63;
  const int wave = t >> 6;
  const int r = lane & 15;
  const int g = lane >> 4;
  for (int k0 = 0; k0 < HID; k0 += 32) {
#pragma unroll
    for (int i = 0; i < 4; ++i) {
      int chunk = i * 128 + t;
      load_lds16(A + (size_t)(m0 + (chunk >> 2)) * HID + k0 + ((chunk & 3) << 3),
                 As + chunk * 8);
    }
#pragma unroll
    for (int i = 0; i < 2; ++i) {
      int chunk = i * 128 + t;
      load_lds16(Bw + (size_t)(n0 + (chunk >> 2)) * HID + k0 + ((chunk & 3) << 3),
                 Bs + chunk * 8);
    }
    __syncthreads();
    bf16x8 af[4], bfr[4];
#pragma unroll
    for (int mt = 0; mt < 4; ++mt)
      af[mt] = *reinterpret_cast<const bf16x8*>(As + (wave * 64 + mt * 16 + r) * 32 + g * 8);
#pragma unroll
    for (int nt = 0; nt < 4; ++nt)
      bfr[nt] = *reinterpret_cast<const bf16x8*>(Bs + (nt * 16 + r) * 32 + g * 8);
#pragma unroll
    for (int mt = 0; mt < 4; ++mt)
#pragma unroll
      for (int nt = 0; nt < 4; ++nt)
        acc[mt][nt] = __builtin_amdgcn_mfma_f32_16x16x32_bf16(af[mt], bfr[nt], acc[mt][nt], 0, 0, 0);
    __syncthreads();
  }
}

// ---------------- QKV projection (z = 0/1/2 -> Q/K/V) -----------------------
__global__ __launch_bounds__(128) void gemm_qkv(
    const unsigned short* __restrict__ xb, const unsigned short* __restrict__ wb,
    const float* __restrict__ bq, const float* __restrict__ bk,
    const float* __restrict__ bv, unsigned short* __restrict__ Qd,
    unsigned short* __restrict__ Kd, unsigned short* __restrict__ Vt) {
  __shared__ __align__(16) unsigned short As[128 * 32];
  __shared__ __align__(16) unsigned short Bs[64 * 32];
  const int z = blockIdx.z;
  const unsigned short* W = wb + (size_t)z * (HID * HID);
  const float* bias = (z == 0) ? bq : (z == 1) ? bk : bv;
  const int m0 = blockIdx.y * 128, n0 = blockIdx.x * 64;
  f32x4 zv = {0.f, 0.f, 0.f, 0.f};
  f32x4 acc[4][4];
#pragma unroll
  for (int a = 0; a < 4; ++a)
#pragma unroll
    for (int c = 0; c < 4; ++c) acc[a][c] = zv;
  gemm_bt_core(xb, W, m0, n0, As, Bs, acc);
  const int lane = threadIdx.x & 63, wave = threadIdx.x >> 6;
  const int r = lane & 15, g = lane >> 4;
#pragma unroll
  for (int mt = 0; mt < 4; ++mt) {
#pragma unroll
    for (int nt = 0; nt < 4; ++nt) {
      int n = n0 + nt * 16 + r;
      float bb = bias[n];
      int h = n >> 6, d = n & 63;
#pragma unroll
      for (int i = 0; i < 4; ++i) {
        int m = m0 + wave * 64 + mt * 16 + g * 4 + i;
        int b = m >> 11, s = m & 2047;
        int bh = b * NH + h;
        unsigned short val = f2bf(acc[mt][nt][i] + bb);
        if (z == 0)      Qd[((size_t)bh * SEQ + s) * HD + d] = val;
        else if (z == 1) Kd[((size_t)bh * SEQ + s) * HD + d] = val;
        else             Vt[((size_t)bh * HD + d) * SEQ + s] = val;
      }
    }
  }
}

// ---------------- output projection: fp32 out + bias ------------------------
__global__ __launch_bounds__(128) void gemm_out(
    const unsigned short* __restrict__ Ob, const unsigned short* __restrict__ Wob,
    const float* __restrict__ bo, float* __restrict__ out) {
  __shared__ __align__(16) unsigned short As[128 * 32];
  __shared__ __align__(16) unsigned short Bs[64 * 32];
  const int m0 = blockIdx.y * 128, n0 = blockIdx.x * 64;
  f32x4 zv = {0.f, 0.f, 0.f, 0.f};
  f32x4 acc[4][4];
#pragma unroll
  for (int a = 0; a < 4; ++a)
#pragma unroll
    for (int c = 0; c < 4; ++c) acc[a][c] = zv;
  gemm_bt_core(Ob, Wob, m0, n0, As, Bs, acc);
  const int lane = threadIdx.x & 63, wave = threadIdx.x >> 6;
  const int r = lane & 15, g = lane >> 4;
#pragma unroll
  for (int mt = 0; mt < 4; ++mt) {
#pragma unroll
    for (int nt = 0; nt < 4; ++nt) {
      int n = n0 + nt * 16 + r;
      float bb = bo[n];
#pragma unroll
      for (int i = 0; i < 4; ++i) {
        int m = m0 + wave * 64 + mt * 16 + g * 4 + i;
        out[(size_t)m * HID + n] = acc[mt][nt][i] + bb;
      }
    }
  }
}

// ---------------- flash attention -------------------------------------------
// grid (S/64, BH). 4 waves/block; wave owns 16 queries. Q,K: [bh][s][64],
// V^T: [bh][64][s]. Online softmax fp32; P through padded LDS into PV MFMA.
__global__ __launch_bounds__(256) void flash_attn(
    const unsigned short* __restrict__ Q, const unsigned short* __restrict__ K,
    const unsigned short* __restrict__ Vt, const int* __restrict__ map,
    const int* __restrict__ mask, unsigned short* __restrict__ O) {
  __shared__ __align__(16) unsigned short P[4][16][88];
  const int bh = blockIdx.y;
  const int lane = threadIdx.x & 63, wave = threadIdx.x >> 6;
  const int r = lane & 15, g = lane >> 4;
  const int q0 = blockIdx.x * 64 + wave * 16;
  const unsigned short* Qb = Q + (size_t)bh * SEQ * HD;
  const unsigned short* Kb = K + (size_t)bh * SEQ * HD;
  const unsigned short* Vb = Vt + (size_t)bh * HD * SEQ;
  bf16x8 qf0 = *reinterpret_cast<const bf16x8*>(Qb + (q0 + r) * HD + g * 8);
  bf16x8 qf1 = *reinterpret_cast<const bf16x8*>(Qb + (q0 + r) * HD + 32 + g * 8);
  f32x4 zv = {0.f, 0.f, 0.f, 0.f};
  float mrun[4], lrun[4];
  f32x4 oacc[4];
#pragma unroll
  for (int i = 0; i < 4; ++i) { mrun[i] = -1e30f; lrun[i] = 0.f; }
#pragma unroll
  for (int dt = 0; dt < 4; ++dt) oacc[dt] = zv;

  for (int kb = 0; kb < SEQ; kb += 64) {
    f32x4 sacc[4];
#pragma unroll
    for (int kt = 0; kt < 4; ++kt) sacc[kt] = zv;
#pragma unroll
    for (int kt = 0; kt < 4; ++kt) {
      const unsigned short* kp = Kb + (size_t)(kb + kt * 16 + r) * HD;
      bf16x8 kf0 = *reinterpret_cast<const bf16x8*>(kp + g * 8);
      bf16x8 kf1 = *reinterpret_cast<const bf16x8*>(kp + 32 + g * 8);
      sacc[kt] = __builtin_amdgcn_mfma_f32_16x16x32_bf16(qf0, kf0, sacc[kt], 0, 0, 0);
      sacc[kt] = __builtin_amdgcn_mfma_f32_16x16x32_bf16(qf1, kf1, sacc[kt], 0, 0, 0);
    }
    float p[4][4];
#pragma unroll
    for (int kt = 0; kt < 4; ++kt)
#pragma unroll
      for (int i = 0; i < 4; ++i) p[kt][i] = sacc[kt][i] * 0.125f;
    if (map[blockIdx.x * 32 + (kb >> 6)]) {  // slow path only if mask has zeros
#pragma unroll
      for (int kt = 0; kt < 4; ++kt)
#pragma unroll
        for (int i = 0; i < 4; ++i)
          if (mask[(size_t)(q0 + g * 4 + i) * SEQ + kb + kt * 16 + r] == 0)
            p[kt][i] = -__builtin_inff();
    }
    float pm[4];
#pragma unroll
    for (int i = 0; i < 4; ++i)
      pm[i] = fmaxf(fmaxf(p[0][i], p[1][i]), fmaxf(p[2][i], p[3][i]));
#pragma unroll
    for (int off = 1; off < 16; off <<= 1)
#pragma unroll
      for (int i = 0; i < 4; ++i) pm[i] = fmaxf(pm[i], __shfl_xor(pm[i], off, 64));
    float corr[4], psum[4];
#pragma unroll
    for (int i = 0; i < 4; ++i) {
      float mnew = fmaxf(mrun[i], pm[i]);
      corr[i] = __expf(mrun[i] - mnew);
      mrun[i] = mnew;
      psum[i] = 0.f;
    }
#pragma unroll
    for (int kt = 0; kt < 4; ++kt)
#pragma unroll
      for (int i = 0; i < 4; ++i) {
        p[kt][i] = __expf(p[kt][i] - mrun[i]);
        psum[i] += p[kt][i];
      }
#pragma unroll
    for (int off = 1; off < 16; off <<= 1)
#pragma unroll
      for (int i = 0; i < 4; ++i) psum[i] += __shfl_xor(psum[i], off, 64);
#pragma unroll
    for (int i = 0; i < 4; ++i) lrun[i] = lrun[i] * corr[i] + psum[i];
#pragma unroll
    for (int dt = 0; dt < 4; ++dt)
#pragma unroll
      for (int i = 0; i < 4; ++i) oacc[dt][i] *= corr[i];
    // transpose P through LDS: D-layout (row=g*4+i, col=kt*16+r) -> A-layout
#pragma unroll
    for (int kt = 0; kt < 4; ++kt)
#pragma unroll
      for (int i = 0; i < 4; ++i) P[wave][g * 4 + i][kt * 16 + r] = f2bf(p[kt][i]);
    asm volatile("s_waitcnt lgkmcnt(0)" ::: "memory");
    __builtin_amdgcn_sched_barrier(0);
    bf16x8 pf0 = *reinterpret_cast<const bf16x8*>(&P[wave][r][g * 8]);
    bf16x8 pf1 = *reinterpret_cast<const bf16x8*>(&P[wave][r][32 + g * 8]);
#pragma unroll
    for (int dt = 0; dt < 4; ++dt) {
      const unsigned short* vp = Vb + (size_t)(dt * 16 + r) * SEQ + kb;
      bf16x8 vf0 = *reinterpret_cast<const bf16x8*>(vp + g * 8);
      bf16x8 vf1 = *reinterpret_cast<const bf16x8*>(vp + 32 + g * 8);
      oacc[dt] = __builtin_amdgcn_mfma_f32_16x16x32_bf16(pf0, vf0, oacc[dt], 0, 0, 0);
      oacc[dt] = __builtin_amdgcn_mfma_f32_16x16x32_bf16(pf1, vf1, oacc[dt], 0, 0, 0);
    }
  }
  const int b = bh >> 4, h = bh & 15;
#pragma unroll
  for (int dt = 0; dt < 4; ++dt)
#pragma unroll
    for (int i = 0; i < 4; ++i) {
      int q = q0 + g * 4 + i;
      float ov = oacc[dt][i] / lrun[i];
      O[((size_t)(b * SEQ + q)) * HID + h * HD + dt * 16 + r] = f2bf(ov);
    }
}

// ---------------- launch -----------------------------------------------------
extern "C" void kernel_launch(void* const* d_in, const int* in_sizes, int n_in,
                              void* d_out, int out_size, void* d_ws, size_t ws_size,
                              hipStream_t stream) {
  const float* x    = (const float*)d_in[0];
  const int*   mask = (const int*)d_in[1];
  const float* Wq   = (const float*)d_in[2];
  const float* bq   = (const float*)d_in[3];
  const float* Wk   = (const float*)d_in[4];
  const float* bk   = (const float*)d_in[5];
  const float* Wv   = (const float*)d_in[6];
  const float* bv   = (const float*)d_in[7];
  const float* Wo   = (const float*)d_in[8];
  const float* bo   = (const float*)d_in[9];
  float* out = (float*)d_out;

  unsigned short* ws = (unsigned short*)d_ws;
  unsigned short* xb = ws;                      // 4194304 bf16
  unsigned short* wb = ws + 4194304;            // 4 x 1048576 (Wq,Wk,Wv,Wo)
  unsigned short* Qd = ws + 8388608;            // [32][2048][64]
  unsigned short* Kd = ws + 12582912;           // [32][2048][64]
  unsigned short* Vt = ws + 16777216;           // [32][64][2048]
  unsigned short* Ob = ws + 20971520;           // [4096][1024]
  int* map = (int*)(ws + 25165824);             // [32][32]

  convert_all<<<8192, 256, 0, stream>>>(x, Wq, Wk, Wv, Wo, ws);
  mask_reduce<<<dim3(32, 32), 256, 0, stream>>>(mask, map);
  gemm_qkv<<<dim3(16, 32, 3), 128, 0, stream>>>(xb, wb, bq, bk, bv, Qd, Kd, Vt);
  flash_attn<<<dim3(32, 32), 256, 0, stream>>>(Qd, Kd, Vt, map, mask, Ob);
  gemm_out<<<dim3(16, 32), 128, 0, stream>>>(Ob, wb + 3 * 1048576, bo, out);
}

// Round 2
// 194.176 us; speedup vs baseline: 1.6180x; 1.6180x over previous
//
#include <hip/hip_runtime.h>
#include <stdint.h>
#include <stddef.h>

#define SEQ 2048
#define NH 16
#define HD 64
#define NB 2
#define HID 1024

typedef short bf16x8 __attribute__((ext_vector_type(8)));
typedef float f32x4 __attribute__((ext_vector_type(4)));

__device__ __forceinline__ unsigned short f2bf(float f) {
  unsigned u = __float_as_uint(f);
  u += 0x7fffu + ((u >> 16) & 1u);
  return (unsigned short)(u >> 16);
}

__device__ __forceinline__ void load_lds16(const void* g, void* l) {
  __builtin_amdgcn_global_load_lds(
      (const __attribute__((address_space(1))) unsigned int*)g,
      (__attribute__((address_space(3))) unsigned int*)l, 16, 0, 0);
}

// ---------------- fp32 -> bf16 conversion of x and the 4 weight matrices ----
__global__ __launch_bounds__(256) void convert_all(
    const float* __restrict__ x, const float* __restrict__ wq,
    const float* __restrict__ wk, const float* __restrict__ wv,
    const float* __restrict__ wo, unsigned short* __restrict__ dst) {
  long i = ((long)blockIdx.x * 256 + threadIdx.x) * 4;
  const float* src; long off;
  if (i < 4194304L)      { src = x;  off = i; }
  else if (i < 5242880L) { src = wq; off = i - 4194304L; }
  else if (i < 6291456L) { src = wk; off = i - 5242880L; }
  else if (i < 7340032L) { src = wv; off = i - 6291456L; }
  else                   { src = wo; off = i - 7340032L; }
  float4 v = *reinterpret_cast<const float4*>(src + off);
  ushort4 o;
  o.x = f2bf(v.x); o.y = f2bf(v.y); o.z = f2bf(v.z); o.w = f2bf(v.w);
  *reinterpret_cast<ushort4*>(dst + i) = o;
}

// ---------------- mask -> 64x64-block "any zero" map ------------------------
__global__ __launch_bounds__(256) void mask_reduce(const int* __restrict__ mask,
                                                   int* __restrict__ map) {
  const int qb = blockIdx.y, kb = blockIdx.x;
  int bad = 0;
  for (int i = threadIdx.x; i < 4096; i += 256) {
    int qq = i >> 6, kk = i & 63;
    bad |= (mask[(size_t)(qb * 64 + qq) * SEQ + kb * 64 + kk] == 0);
  }
  __shared__ int red[4];
  unsigned long long any = __ballot(bad);
  if ((threadIdx.x & 63) == 0) red[threadIdx.x >> 6] = (any != 0ULL);
  __syncthreads();
  if (threadIdx.x == 0) map[qb * 32 + kb] = red[0] | red[1] | red[2] | red[3];
}

// ---------------- shared GEMM main loop: C(128x64) = A * B^T ----------------
__device__ __forceinline__ void gemm_bt_core(
    const unsigned short* __restrict__ A, const unsigned short* __restrict__ Bw,
    int m0, int n0, unsigned short* As, unsigned short* Bs, f32x4 acc[4][4]) {
  const int t = threadIdx.x;
  const int lane = t & 63;
  const int wave = t >> 6;
  const int r = lane & 15;
  const int g = lane >> 4;
  for (int k0 = 0; k0 < HID; k0 += 32) {
#pragma unroll
    for (int i = 0; i < 4; ++i) {
      int chunk = i * 128 + t;
      load_lds16(A + (size_t)(m0 + (chunk >> 2)) * HID + k0 + ((chunk & 3) << 3),
                 As + chunk * 8);
    }
#pragma unroll
    for (int i = 0; i < 2; ++i) {
      int chunk = i * 128 + t;
      load_lds16(Bw + (size_t)(n0 + (chunk >> 2)) * HID + k0 + ((chunk & 3) << 3),
                 Bs + chunk * 8);
    }
    __syncthreads();
    bf16x8 af[4], bfr[4];
#pragma unroll
    for (int mt = 0; mt < 4; ++mt)
      af[mt] = *reinterpret_cast<const bf16x8*>(As + (wave * 64 + mt * 16 + r) * 32 + g * 8);
#pragma unroll
    for (int nt = 0; nt < 4; ++nt)
      bfr[nt] = *reinterpret_cast<const bf16x8*>(Bs + (nt * 16 + r) * 32 + g * 8);
#pragma unroll
    for (int mt = 0; mt < 4; ++mt)
#pragma unroll
      for (int nt = 0; nt < 4; ++nt)
        acc[mt][nt] = __builtin_amdgcn_mfma_f32_16x16x32_bf16(af[mt], bfr[nt], acc[mt][nt], 0, 0, 0);
    __syncthreads();
  }
}

// ---------------- QKV projection (z = 0/1/2 -> Q/K/V) -----------------------
__global__ __launch_bounds__(128) void gemm_qkv(
    const unsigned short* __restrict__ xb, const unsigned short* __restrict__ wb,
    const float* __restrict__ bq, const float* __restrict__ bk,
    const float* __restrict__ bv, unsigned short* __restrict__ Qd,
    unsigned short* __restrict__ Kd, unsigned short* __restrict__ Vt) {
  __shared__ __align__(16) unsigned short As[128 * 32];
  __shared__ __align__(16) unsigned short Bs[64 * 32];
  const int z = blockIdx.z;
  const unsigned short* W = wb + (size_t)z * (HID * HID);
  const float* bias = (z == 0) ? bq : (z == 1) ? bk : bv;
  const int m0 = blockIdx.y * 128, n0 = blockIdx.x * 64;
  f32x4 zv = {0.f, 0.f, 0.f, 0.f};
  f32x4 acc[4][4];
#pragma unroll
  for (int a = 0; a < 4; ++a)
#pragma unroll
    for (int c = 0; c < 4; ++c) acc[a][c] = zv;
  gemm_bt_core(xb, W, m0, n0, As, Bs, acc);
  const int lane = threadIdx.x & 63, wave = threadIdx.x >> 6;
  const int r = lane & 15, g = lane >> 4;
#pragma unroll
  for (int mt = 0; mt < 4; ++mt) {
#pragma unroll
    for (int nt = 0; nt < 4; ++nt) {
      int n = n0 + nt * 16 + r;
      float bb = bias[n];
      int h = n >> 6, d = n & 63;
#pragma unroll
      for (int i = 0; i < 4; ++i) {
        int m = m0 + wave * 64 + mt * 16 + g * 4 + i;
        int b = m >> 11, s = m & 2047;
        int bh = b * NH + h;
        unsigned short val = f2bf(acc[mt][nt][i] + bb);
        if (z == 0)      Qd[((size_t)bh * SEQ + s) * HD + d] = val;
        else if (z == 1) Kd[((size_t)bh * SEQ + s) * HD + d] = val;
        else             Vt[((size_t)bh * HD + d) * SEQ + s] = val;
      }
    }
  }
}

// ---------------- output projection: fp32 out + bias ------------------------
__global__ __launch_bounds__(128) void gemm_out(
    const unsigned short* __restrict__ Ob, const unsigned short* __restrict__ Wob,
    const float* __restrict__ bo, float* __restrict__ out) {
  __shared__ __align__(16) unsigned short As[128 * 32];
  __shared__ __align__(16) unsigned short Bs[64 * 32];
  const int m0 = blockIdx.y * 128, n0 = blockIdx.x * 64;
  f32x4 zv = {0.f, 0.f, 0.f, 0.f};
  f32x4 acc[4][4];
#pragma unroll
  for (int a = 0; a < 4; ++a)
#pragma unroll
    for (int c = 0; c < 4; ++c) acc[a][c] = zv;
  gemm_bt_core(Ob, Wob, m0, n0, As, Bs, acc);
  const int lane = threadIdx.x & 63, wave = threadIdx.x >> 6;
  const int r = lane & 15, g = lane >> 4;
#pragma unroll
  for (int mt = 0; mt < 4; ++mt) {
#pragma unroll
    for (int nt = 0; nt < 4; ++nt) {
      int n = n0 + nt * 16 + r;
      float bb = bo[n];
#pragma unroll
      for (int i = 0; i < 4; ++i) {
        int m = m0 + wave * 64 + mt * 16 + g * 4 + i;
        out[(size_t)m * HID + n] = acc[mt][nt][i] + bb;
      }
    }
  }
}

// ---------------- flash attention v2 -----------------------------------------
// grid (S/128, BH). 4 waves/block; wave owns 32 queries (2x 16-row frags).
// K,V^T tiles (64x64 bf16) staged in LDS via global_load_lds, double-buffered,
// XOR-swizzled (slot ^= row&7; source pre-swizzled, read swizzled).
// Q hoisted to registers. Online softmax fp32; P through padded LDS.
__global__ __launch_bounds__(256, 3) void flash_attn(
    const unsigned short* __restrict__ Q, const unsigned short* __restrict__ K,
    const unsigned short* __restrict__ Vt, const int* __restrict__ map,
    const int* __restrict__ mask, unsigned short* __restrict__ O) {
  __shared__ __align__(16) unsigned short Ks[2][64][64];
  __shared__ __align__(16) unsigned short Vs[2][64][64];
  __shared__ __align__(16) unsigned short Pl[4][32][72];
  const int bh = blockIdx.y;
  const int t = threadIdx.x;
  const int lane = t & 63, wave = t >> 6;
  const int r = lane & 15, g = lane >> 4;
  const int q0 = blockIdx.x * 128 + wave * 32;
  const unsigned short* Qb = Q + (size_t)bh * SEQ * HD;
  const unsigned short* Kb = K + (size_t)bh * SEQ * HD;
  const unsigned short* Vb = Vt + (size_t)bh * HD * SEQ;

  // hoist Q: rows q0 + mt*16 + r, d-halves h*32 + g*8
  bf16x8 qf[2][2];
#pragma unroll
  for (int mt = 0; mt < 2; ++mt)
#pragma unroll
    for (int h = 0; h < 2; ++h)
      qf[mt][h] = *reinterpret_cast<const bf16x8*>(
          Qb + (size_t)(q0 + mt * 16 + r) * HD + h * 32 + g * 8);

  f32x4 zv = {0.f, 0.f, 0.f, 0.f};
  f32x4 oacc[4][2];
  float mrun[2][4], lrun[2][4];
#pragma unroll
  for (int mt = 0; mt < 2; ++mt)
#pragma unroll
    for (int i = 0; i < 4; ++i) { mrun[mt][i] = -1e30f; lrun[mt][i] = 0.f; }
#pragma unroll
  for (int dt = 0; dt < 4; ++dt)
#pragma unroll
    for (int mt = 0; mt < 2; ++mt) oacc[dt][mt] = zv;

  // staging decomposition: thread t covers LDS rows (t>>3) and 32+(t>>3),
  // 16B slot (t&7). Source column-slot pre-swizzled so LDS is stored swizzled
  // while global_load_lds writes linearly (rule: swizzle source + read).
  const int srow = t >> 3;
  const int sslot = t & 7;

#define STAGE_K(kbase, buf) do {                                            \
    int c0 = sslot ^ (srow & 7);                                            \
    load_lds16(Kb + (size_t)((kbase) + srow) * HD + c0 * 8,                 \
               &Ks[buf][srow][sslot * 8]);                                  \
    load_lds16(Kb + (size_t)((kbase) + 32 + srow) * HD + c0 * 8,            \
               &Ks[buf][32 + srow][sslot * 8]);                             \
  } while (0)
#define STAGE_V(kbase, buf) do {                                            \
    int c0 = sslot ^ (srow & 7);                                            \
    load_lds16(Vb + (size_t)srow * SEQ + (kbase) + c0 * 8,                  \
               &Vs[buf][srow][sslot * 8]);                                  \
    load_lds16(Vb + (size_t)(32 + srow) * SEQ + (kbase) + c0 * 8,           \
               &Vs[buf][32 + srow][sslot * 8]);                             \
  } while (0)
#define KFR(row, slot) \
  (*reinterpret_cast<const bf16x8*>(&Ks[cur][row][(((slot) ^ ((row) & 7)) << 3)]))
#define VFR(row, slot) \
  (*reinterpret_cast<const bf16x8*>(&Vs[cur][row][(((slot) ^ ((row) & 7)) << 3)]))

  STAGE_K(0, 0);
  STAGE_V(0, 0);
  asm volatile("s_waitcnt vmcnt(0)" ::: "memory");
  __syncthreads();
  int cur = 0;

  for (int kb = 0; kb < SEQ; kb += 64) {
    // prefetch next tile into the other buffer (loads fly across compute)
    if (kb + 64 < SEQ) {
      STAGE_K(kb + 64, cur ^ 1);
      STAGE_V(kb + 64, cur ^ 1);
    }
    // ---- QK^T: S[32q x 64k], k-dim = d (64, two halves) ----
    f32x4 sacc[2][4];
#pragma unroll
    for (int mt = 0; mt < 2; ++mt)
#pragma unroll
      for (int kt = 0; kt < 4; ++kt) sacc[mt][kt] = zv;
#pragma unroll
    for (int kt = 0; kt < 4; ++kt) {
      int row = kt * 16 + r;
      bf16x8 kf0 = KFR(row, g);
      bf16x8 kf1 = KFR(row, 4 + g);
#pragma unroll
      for (int mt = 0; mt < 2; ++mt) {
        sacc[mt][kt] = __builtin_amdgcn_mfma_f32_16x16x32_bf16(qf[mt][0], kf0, sacc[mt][kt], 0, 0, 0);
        sacc[mt][kt] = __builtin_amdgcn_mfma_f32_16x16x32_bf16(qf[mt][1], kf1, sacc[mt][kt], 0, 0, 0);
      }
    }
    // ---- softmax (lane holds q rows (mt,i), k col = kt*16 + r) ----
    float sc[2][4][4];
#pragma unroll
    for (int mt = 0; mt < 2; ++mt)
#pragma unroll
      for (int kt = 0; kt < 4; ++kt)
#pragma unroll
        for (int i = 0; i < 4; ++i) sc[mt][kt][i] = sacc[mt][kt][i] * 0.125f;
    if (map[(q0 >> 6) * 32 + (kb >> 6)]) {  // slow path only if mask has zeros
#pragma unroll
      for (int mt = 0; mt < 2; ++mt)
#pragma unroll
        for (int kt = 0; kt < 4; ++kt)
#pragma unroll
          for (int i = 0; i < 4; ++i)
            if (mask[(size_t)(q0 + mt * 16 + g * 4 + i) * SEQ + kb + kt * 16 + r] == 0)
              sc[mt][kt][i] = -__builtin_inff();
    }
    float pm[2][4];
#pragma unroll
    for (int mt = 0; mt < 2; ++mt)
#pragma unroll
      for (int i = 0; i < 4; ++i)
        pm[mt][i] = fmaxf(fmaxf(sc[mt][0][i], sc[mt][1][i]),
                          fmaxf(sc[mt][2][i], sc[mt][3][i]));
#pragma unroll
    for (int off = 1; off < 16; off <<= 1)
#pragma unroll
      for (int mt = 0; mt < 2; ++mt)
#pragma unroll
        for (int i = 0; i < 4; ++i)
          pm[mt][i] = fmaxf(pm[mt][i], __shfl_xor(pm[mt][i], off, 64));
    float corr[2][4], psum[2][4];
#pragma unroll
    for (int mt = 0; mt < 2; ++mt)
#pragma unroll
      for (int i = 0; i < 4; ++i) {
        float mnew = fmaxf(mrun[mt][i], pm[mt][i]);
        corr[mt][i] = __expf(mrun[mt][i] - mnew);
        mrun[mt][i] = mnew;
        psum[mt][i] = 0.f;
      }
#pragma unroll
    for (int mt = 0; mt < 2; ++mt)
#pragma unroll
      for (int kt = 0; kt < 4; ++kt)
#pragma unroll
        for (int i = 0; i < 4; ++i) {
          sc[mt][kt][i] = __expf(sc[mt][kt][i] - mrun[mt][i]);
          psum[mt][i] += sc[mt][kt][i];
        }
#pragma unroll
    for (int off = 1; off < 16; off <<= 1)
#pragma unroll
      for (int mt = 0; mt < 2; ++mt)
#pragma unroll
        for (int i = 0; i < 4; ++i)
          psum[mt][i] += __shfl_xor(psum[mt][i], off, 64);
#pragma unroll
    for (int mt = 0; mt < 2; ++mt)
#pragma unroll
      for (int i = 0; i < 4; ++i)
        lrun[mt][i] = lrun[mt][i] * corr[mt][i] + psum[mt][i];
#pragma unroll
    for (int dt = 0; dt < 4; ++dt)
#pragma unroll
      for (int mt = 0; mt < 2; ++mt)
#pragma unroll
        for (int i = 0; i < 4; ++i) oacc[dt][mt][i] *= corr[mt][i];
    // ---- P transpose through LDS (row=q, col=k), per-wave buffer ----
#pragma unroll
    for (int mt = 0; mt < 2; ++mt)
#pragma unroll
      for (int kt = 0; kt < 4; ++kt)
#pragma unroll
        for (int i = 0; i < 4; ++i)
          Pl[wave][mt * 16 + g * 4 + i][kt * 16 + r] = f2bf(sc[mt][kt][i]);
    asm volatile("s_waitcnt lgkmcnt(0)" ::: "memory");
    __builtin_amdgcn_sched_barrier(0);
    bf16x8 pf[2][2];
#pragma unroll
    for (int mt = 0; mt < 2; ++mt)
#pragma unroll
      for (int h = 0; h < 2; ++h)
        pf[mt][h] = *reinterpret_cast<const bf16x8*>(&Pl[wave][mt * 16 + r][h * 32 + g * 8]);
    // ---- PV: O += P * V, k-dim = kv (64, two halves) ----
#pragma unroll
    for (int dt = 0; dt < 4; ++dt) {
      int row = dt * 16 + r;
      bf16x8 vf0 = VFR(row, g);
      bf16x8 vf1 = VFR(row, 4 + g);
#pragma unroll
      for (int mt = 0; mt < 2; ++mt) {
        oacc[dt][mt] = __builtin_amdgcn_mfma_f32_16x16x32_bf16(pf[mt][0], vf0, oacc[dt][mt], 0, 0, 0);
        oacc[dt][mt] = __builtin_amdgcn_mfma_f32_16x16x32_bf16(pf[mt][1], vf1, oacc[dt][mt], 0, 0, 0);
      }
    }
    // next tile must be fully landed before we flip buffers
    asm volatile("s_waitcnt vmcnt(0)" ::: "memory");
    __syncthreads();
    cur ^= 1;
  }

  float rl[2][4];
#pragma unroll
  for (int mt = 0; mt < 2; ++mt)
#pragma unroll
    for (int i = 0; i < 4; ++i) rl[mt][i] = 1.0f / lrun[mt][i];
  const int b = bh >> 4, h = bh & 15;
#pragma unroll
  for (int dt = 0; dt < 4; ++dt)
#pragma unroll
    for (int mt = 0; mt < 2; ++mt)
#pragma unroll
      for (int i = 0; i < 4; ++i) {
        int q = q0 + mt * 16 + g * 4 + i;
        O[((size_t)(b * SEQ + q)) * HID + h * HD + dt * 16 + r] =
            f2bf(oacc[dt][mt][i] * rl[mt][i]);
      }
#undef STAGE_K
#undef STAGE_V
#undef KFR
#undef VFR
}

// ---------------- launch -----------------------------------------------------
extern "C" void kernel_launch(void* const* d_in, const int* in_sizes, int n_in,
                              void* d_out, int out_size, void* d_ws, size_t ws_size,
                              hipStream_t stream) {
  const float* x    = (const float*)d_in[0];
  const int*   mask = (const int*)d_in[1];
  const float* Wq   = (const float*)d_in[2];
  const float* bq   = (const float*)d_in[3];
  const float* Wk   = (const float*)d_in[4];
  const float* bk   = (const float*)d_in[5];
  const float* Wv   = (const float*)d_in[6];
  const float* bv   = (const float*)d_in[7];
  const float* Wo   = (const float*)d_in[8];
  const float* bo   = (const float*)d_in[9];
  float* out = (float*)d_out;

  unsigned short* ws = (unsigned short*)d_ws;
  unsigned short* xb = ws;                      // 4194304 bf16
  unsigned short* wb = ws + 4194304;            // 4 x 1048576 (Wq,Wk,Wv,Wo)
  unsigned short* Qd = ws + 8388608;            // [32][2048][64]
  unsigned short* Kd = ws + 12582912;           // [32][2048][64]
  unsigned short* Vt = ws + 16777216;           // [32][64][2048]
  unsigned short* Ob = ws + 20971520;           // [4096][1024]
  int* map = (int*)(ws + 25165824);             // [32][32]

  convert_all<<<8192, 256, 0, stream>>>(x, Wq, Wk, Wv, Wo, ws);
  mask_reduce<<<dim3(32, 32), 256, 0, stream>>>(mask, map);
  gemm_qkv<<<dim3(16, 32, 3), 128, 0, stream>>>(xb, wb, bq, bk, bv, Qd, Kd, Vt);
  flash_attn<<<dim3(16, 32), 256, 0, stream>>>(Qd, Kd, Vt, map, mask, Ob);
  gemm_out<<<dim3(16, 32), 128, 0, stream>>>(Ob, wb + 3 * 1048576, bo, out);
}

// Round 3
// 164.241 us; speedup vs baseline: 1.9129x; 1.1823x over previous
//
#include <hip/hip_runtime.h>
#include <stdint.h>
#include <stddef.h>

#define SEQ 2048
#define NH 16
#define HD 64
#define NB 2
#define HID 1024

typedef short bf16x8 __attribute__((ext_vector_type(8)));
typedef float f32x4 __attribute__((ext_vector_type(4)));

__device__ __forceinline__ unsigned short f2bf(float f) {
  unsigned u = __float_as_uint(f);
  u += 0x7fffu + ((u >> 16) & 1u);
  return (unsigned short)(u >> 16);
}

__device__ __forceinline__ void load_lds16(const void* g, void* l) {
  __builtin_amdgcn_global_load_lds(
      (const __attribute__((address_space(1))) unsigned int*)g,
      (__attribute__((address_space(3))) unsigned int*)l, 16, 0, 0);
}

// ---------------- fp32 -> bf16 conversion of x and the 4 weight matrices ----
__global__ __launch_bounds__(256) void convert_all(
    const float* __restrict__ x, const float* __restrict__ wq,
    const float* __restrict__ wk, const float* __restrict__ wv,
    const float* __restrict__ wo, unsigned short* __restrict__ dst) {
  long i = ((long)blockIdx.x * 256 + threadIdx.x) * 4;
  const float* src; long off;
  if (i < 4194304L)      { src = x;  off = i; }
  else if (i < 5242880L) { src = wq; off = i - 4194304L; }
  else if (i < 6291456L) { src = wk; off = i - 5242880L; }
  else if (i < 7340032L) { src = wv; off = i - 6291456L; }
  else                   { src = wo; off = i - 7340032L; }
  float4 v = *reinterpret_cast<const float4*>(src + off);
  ushort4 o;
  o.x = f2bf(v.x); o.y = f2bf(v.y); o.z = f2bf(v.z); o.w = f2bf(v.w);
  *reinterpret_cast<ushort4*>(dst + i) = o;
}

// ---------------- mask -> 64x64-block "any zero" map ------------------------
__global__ __launch_bounds__(256) void mask_reduce(const int* __restrict__ mask,
                                                   int* __restrict__ map) {
  const int qb = blockIdx.y, kb = blockIdx.x;
  int bad = 0;
  for (int i = threadIdx.x; i < 4096; i += 256) {
    int qq = i >> 6, kk = i & 63;
    bad |= (mask[(size_t)(qb * 64 + qq) * SEQ + kb * 64 + kk] == 0);
  }
  __shared__ int red[4];
  unsigned long long any = __ballot(bad);
  if ((threadIdx.x & 63) == 0) red[threadIdx.x >> 6] = (any != 0ULL);
  __syncthreads();
  if (threadIdx.x == 0) map[qb * 32 + kb] = red[0] | red[1] | red[2] | red[3];
}

// ---------------- shared GEMM main loop: C(128x64) = A * B^T ----------------
__device__ __forceinline__ void gemm_bt_core(
    const unsigned short* __restrict__ A, const unsigned short* __restrict__ Bw,
    int m0, int n0, unsigned short* As, unsigned short* Bs, f32x4 acc[4][4]) {
  const int t = threadIdx.x;
  const int lane = t & 63;
  const int wave = t >> 6;
  const int r = lane & 15;
  const int g = lane >> 4;
  for (int k0 = 0; k0 < HID; k0 += 32) {
#pragma unroll
    for (int i = 0; i < 4; ++i) {
      int chunk = i * 128 + t;
      load_lds16(A + (size_t)(m0 + (chunk >> 2)) * HID + k0 + ((chunk & 3) << 3),
                 As + chunk * 8);
    }
#pragma unroll
    for (int i = 0; i < 2; ++i) {
      int chunk = i * 128 + t;
      load_lds16(Bw + (size_t)(n0 + (chunk >> 2)) * HID + k0 + ((chunk & 3) << 3),
                 Bs + chunk * 8);
    }
    __syncthreads();
    bf16x8 af[4], bfr[4];
#pragma unroll
    for (int mt = 0; mt < 4; ++mt)
      af[mt] = *reinterpret_cast<const bf16x8*>(As + (wave * 64 + mt * 16 + r) * 32 + g * 8);
#pragma unroll
    for (int nt = 0; nt < 4; ++nt)
      bfr[nt] = *reinterpret_cast<const bf16x8*>(Bs + (nt * 16 + r) * 32 + g * 8);
#pragma unroll
    for (int mt = 0; mt < 4; ++mt)
#pragma unroll
      for (int nt = 0; nt < 4; ++nt)
        acc[mt][nt] = __builtin_amdgcn_mfma_f32_16x16x32_bf16(af[mt], bfr[nt], acc[mt][nt], 0, 0, 0);
    __syncthreads();
  }
}

// ---------------- QKV projection (z = 0/1/2 -> Q/K/V) -----------------------
// Q output is pre-scaled by 1/8 (folds the attention scale into the GEMM).
__global__ __launch_bounds__(128) void gemm_qkv(
    const unsigned short* __restrict__ xb, const unsigned short* __restrict__ wb,
    const float* __restrict__ bq, const float* __restrict__ bk,
    const float* __restrict__ bv, unsigned short* __restrict__ Qd,
    unsigned short* __restrict__ Kd, unsigned short* __restrict__ Vt) {
  __shared__ __align__(16) unsigned short As[128 * 32];
  __shared__ __align__(16) unsigned short Bs[64 * 32];
  const int z = blockIdx.z;
  const unsigned short* W = wb + (size_t)z * (HID * HID);
  const float* bias = (z == 0) ? bq : (z == 1) ? bk : bv;
  const float scl = (z == 0) ? 0.125f : 1.0f;
  const int m0 = blockIdx.y * 128, n0 = blockIdx.x * 64;
  f32x4 zv = {0.f, 0.f, 0.f, 0.f};
  f32x4 acc[4][4];
#pragma unroll
  for (int a = 0; a < 4; ++a)
#pragma unroll
    for (int c = 0; c < 4; ++c) acc[a][c] = zv;
  gemm_bt_core(xb, W, m0, n0, As, Bs, acc);
  const int lane = threadIdx.x & 63, wave = threadIdx.x >> 6;
  const int r = lane & 15, g = lane >> 4;
#pragma unroll
  for (int mt = 0; mt < 4; ++mt) {
#pragma unroll
    for (int nt = 0; nt < 4; ++nt) {
      int n = n0 + nt * 16 + r;
      float bb = bias[n];
      int h = n >> 6, d = n & 63;
#pragma unroll
      for (int i = 0; i < 4; ++i) {
        int m = m0 + wave * 64 + mt * 16 + g * 4 + i;
        int b = m >> 11, s = m & 2047;
        int bh = b * NH + h;
        unsigned short val = f2bf((acc[mt][nt][i] + bb) * scl);
        if (z == 0)      Qd[((size_t)bh * SEQ + s) * HD + d] = val;
        else if (z == 1) Kd[((size_t)bh * SEQ + s) * HD + d] = val;
        else             Vt[((size_t)bh * HD + d) * SEQ + s] = val;
      }
    }
  }
}

// ---------------- output projection: fp32 out + bias ------------------------
__global__ __launch_bounds__(128) void gemm_out(
    const unsigned short* __restrict__ Ob, const unsigned short* __restrict__ Wob,
    const float* __restrict__ bo, float* __restrict__ out) {
  __shared__ __align__(16) unsigned short As[128 * 32];
  __shared__ __align__(16) unsigned short Bs[64 * 32];
  const int m0 = blockIdx.y * 128, n0 = blockIdx.x * 64;
  f32x4 zv = {0.f, 0.f, 0.f, 0.f};
  f32x4 acc[4][4];
#pragma unroll
  for (int a = 0; a < 4; ++a)
#pragma unroll
    for (int c = 0; c < 4; ++c) acc[a][c] = zv;
  gemm_bt_core(Ob, Wob, m0, n0, As, Bs, acc);
  const int lane = threadIdx.x & 63, wave = threadIdx.x >> 6;
  const int r = lane & 15, g = lane >> 4;
#pragma unroll
  for (int mt = 0; mt < 4; ++mt) {
#pragma unroll
    for (int nt = 0; nt < 4; ++nt) {
      int n = n0 + nt * 16 + r;
      float bb = bo[n];
#pragma unroll
      for (int i = 0; i < 4; ++i) {
        int m = m0 + wave * 64 + mt * 16 + g * 4 + i;
        out[(size_t)m * HID + n] = acc[mt][nt][i] + bb;
      }
    }
  }
}

// ---------------- flash attention v3 -----------------------------------------
// grid (S/128, BH), 512 threads = 8 waves; wave owns 16 queries.
// K,V^T 64x64 bf16 tiles in LDS (global_load_lds, double-buffered, XOR-swizzled
// source+read). Row-sum via MFMA with a ones fragment; defer-max rescale (THR=8);
// setprio around MFMA clusters. Q pre-scaled by 1/8 in projection.
__global__ __launch_bounds__(512, 4) void flash_attn(
    const unsigned short* __restrict__ Q, const unsigned short* __restrict__ K,
    const unsigned short* __restrict__ Vt, const int* __restrict__ map,
    const int* __restrict__ mask, unsigned short* __restrict__ O) {
  __shared__ __align__(16) unsigned short Ks[2][64][64];
  __shared__ __align__(16) unsigned short Vs[2][64][64];
  __shared__ __align__(16) unsigned short Pl[8][16][72];
  const int bh = blockIdx.y;
  const int t = threadIdx.x;
  const int lane = t & 63, wave = t >> 6;
  const int r = lane & 15, g = lane >> 4;
  const int q0 = blockIdx.x * 128 + wave * 16;
  const unsigned short* Qb = Q + (size_t)bh * SEQ * HD;
  const unsigned short* Kb = K + (size_t)bh * SEQ * HD;
  const unsigned short* Vb = Vt + (size_t)bh * HD * SEQ;

  bf16x8 qf[2];
#pragma unroll
  for (int h = 0; h < 2; ++h)
    qf[h] = *reinterpret_cast<const bf16x8*>(Qb + (size_t)(q0 + r) * HD + h * 32 + g * 8);

  bf16x8 onesf;
#pragma unroll
  for (int j = 0; j < 8; ++j) onesf[j] = (short)0x3F80;  // bf16 1.0

  f32x4 zv = {0.f, 0.f, 0.f, 0.f};
  f32x4 oacc[4];
  float mrun[4], lrun[4];
#pragma unroll
  for (int i = 0; i < 4; ++i) { mrun[i] = -1e30f; lrun[i] = 0.f; }
#pragma unroll
  for (int dt = 0; dt < 4; ++dt) oacc[dt] = zv;

  // staging: 512 threads cover 64 rows x 8 16B-slots in one shot.
  const int srow = t >> 3;
  const int sslot = t & 7;

#define STAGE_K(kbase, buf) do {                                            \
    int c0 = sslot ^ (srow & 7);                                            \
    load_lds16(Kb + (size_t)((kbase) + srow) * HD + c0 * 8,                 \
               &Ks[buf][srow][sslot * 8]);                                  \
  } while (0)
#define STAGE_V(kbase, buf) do {                                            \
    int c0 = sslot ^ (srow & 7);                                            \
    load_lds16(Vb + (size_t)srow * SEQ + (kbase) + c0 * 8,                  \
               &Vs[buf][srow][sslot * 8]);                                  \
  } while (0)
#define KFR(row, slot) \
  (*reinterpret_cast<const bf16x8*>(&Ks[cur][row][(((slot) ^ ((row) & 7)) << 3)]))
#define VFR(row, slot) \
  (*reinterpret_cast<const bf16x8*>(&Vs[cur][row][(((slot) ^ ((row) & 7)) << 3)]))

  STAGE_K(0, 0);
  STAGE_V(0, 0);
  asm volatile("s_waitcnt vmcnt(0)" ::: "memory");
  __syncthreads();
  int cur = 0;

  for (int kb = 0; kb < SEQ; kb += 64) {
    if (kb + 64 < SEQ) {
      STAGE_K(kb + 64, cur ^ 1);
      STAGE_V(kb + 64, cur ^ 1);
    }
    // ---- QK^T: S[16q x 64k] (Q pre-scaled by 1/8) ----
    f32x4 sacc[4];
#pragma unroll
    for (int kt = 0; kt < 4; ++kt) sacc[kt] = zv;
    __builtin_amdgcn_s_setprio(1);
#pragma unroll
    for (int kt = 0; kt < 4; ++kt) {
      int row = kt * 16 + r;
      bf16x8 kf0 = KFR(row, g);
      bf16x8 kf1 = KFR(row, 4 + g);
      sacc[kt] = __builtin_amdgcn_mfma_f32_16x16x32_bf16(qf[0], kf0, sacc[kt], 0, 0, 0);
      sacc[kt] = __builtin_amdgcn_mfma_f32_16x16x32_bf16(qf[1], kf1, sacc[kt], 0, 0, 0);
    }
    __builtin_amdgcn_s_setprio(0);
    // ---- softmax: lane holds q rows g*4+i, k col kt*16+r ----
    float sc[4][4];
#pragma unroll
    for (int kt = 0; kt < 4; ++kt)
#pragma unroll
      for (int i = 0; i < 4; ++i) sc[kt][i] = sacc[kt][i];
    if (map[(q0 >> 6) * 32 + (kb >> 6)]) {  // slow path only if mask has zeros
#pragma unroll
      for (int kt = 0; kt < 4; ++kt)
#pragma unroll
        for (int i = 0; i < 4; ++i)
          if (mask[(size_t)(q0 + g * 4 + i) * SEQ + kb + kt * 16 + r] == 0)
            sc[kt][i] = -__builtin_inff();
    }
    float pm[4];
#pragma unroll
    for (int i = 0; i < 4; ++i)
      pm[i] = fmaxf(fmaxf(sc[0][i], sc[1][i]), fmaxf(sc[2][i], sc[3][i]));
#pragma unroll
    for (int off = 1; off < 16; off <<= 1)
#pragma unroll
      for (int i = 0; i < 4; ++i) pm[i] = fmaxf(pm[i], __shfl_xor(pm[i], off, 64));
    // defer-max: only rescale when the tile max beats the running max by > 8
    int ok = 1;
#pragma unroll
    for (int i = 0; i < 4; ++i) ok &= (pm[i] <= mrun[i] + 8.0f);
    if (!__all(ok)) {
#pragma unroll
      for (int i = 0; i < 4; ++i) {
        float mnew = fmaxf(mrun[i], pm[i]);
        float corr = __expf(mrun[i] - mnew);
        mrun[i] = mnew;
        lrun[i] *= corr;
#pragma unroll
        for (int dt = 0; dt < 4; ++dt) oacc[dt][i] *= corr;
      }
    }
#pragma unroll
    for (int kt = 0; kt < 4; ++kt)
#pragma unroll
      for (int i = 0; i < 4; ++i) sc[kt][i] = __expf(sc[kt][i] - mrun[i]);
    // ---- P transpose through per-wave LDS buffer ----
#pragma unroll
    for (int kt = 0; kt < 4; ++kt)
#pragma unroll
      for (int i = 0; i < 4; ++i)
        Pl[wave][g * 4 + i][kt * 16 + r] = f2bf(sc[kt][i]);
    asm volatile("s_waitcnt lgkmcnt(0)" ::: "memory");
    __builtin_amdgcn_sched_barrier(0);
    bf16x8 pf[2];
#pragma unroll
    for (int h = 0; h < 2; ++h)
      pf[h] = *reinterpret_cast<const bf16x8*>(&Pl[wave][r][h * 32 + g * 8]);
    // ---- PV + row-sum-by-MFMA ----
    f32x4 lsum = zv;
    __builtin_amdgcn_s_setprio(1);
    lsum = __builtin_amdgcn_mfma_f32_16x16x32_bf16(pf[0], onesf, lsum, 0, 0, 0);
    lsum = __builtin_amdgcn_mfma_f32_16x16x32_bf16(pf[1], onesf, lsum, 0, 0, 0);
#pragma unroll
    for (int dt = 0; dt < 4; ++dt) {
      int row = dt * 16 + r;
      bf16x8 vf0 = VFR(row, g);
      bf16x8 vf1 = VFR(row, 4 + g);
      oacc[dt] = __builtin_amdgcn_mfma_f32_16x16x32_bf16(pf[0], vf0, oacc[dt], 0, 0, 0);
      oacc[dt] = __builtin_amdgcn_mfma_f32_16x16x32_bf16(pf[1], vf1, oacc[dt], 0, 0, 0);
    }
    __builtin_amdgcn_s_setprio(0);
#pragma unroll
    for (int i = 0; i < 4; ++i) lrun[i] += lsum[i];
    // next tile must be fully landed before we flip buffers
    asm volatile("s_waitcnt vmcnt(0)" ::: "memory");
    __syncthreads();
    cur ^= 1;
  }

  float rl[4];
#pragma unroll
  for (int i = 0; i < 4; ++i) rl[i] = 1.0f / lrun[i];
  const int b = bh >> 4, h = bh & 15;
#pragma unroll
  for (int dt = 0; dt < 4; ++dt)
#pragma unroll
    for (int i = 0; i < 4; ++i) {
      int q = q0 + g * 4 + i;
      O[((size_t)(b * SEQ + q)) * HID + h * HD + dt * 16 + r] =
          f2bf(oacc[dt][i] * rl[i]);
    }
#undef STAGE_K
#undef STAGE_V
#undef KFR
#undef VFR
}

// ---------------- launch -----------------------------------------------------
extern "C" void kernel_launch(void* const* d_in, const int* in_sizes, int n_in,
                              void* d_out, int out_size, void* d_ws, size_t ws_size,
                              hipStream_t stream) {
  const float* x    = (const float*)d_in[0];
  const int*   mask = (const int*)d_in[1];
  const float* Wq   = (const float*)d_in[2];
  const float* bq   = (const float*)d_in[3];
  const float* Wk   = (const float*)d_in[4];
  const float* bk   = (const float*)d_in[5];
  const float* Wv   = (const float*)d_in[6];
  const float* bv   = (const float*)d_in[7];
  const float* Wo   = (const float*)d_in[8];
  const float* bo   = (const float*)d_in[9];
  float* out = (float*)d_out;

  unsigned short* ws = (unsigned short*)d_ws;
  unsigned short* xb = ws;                      // 4194304 bf16
  unsigned short* wb = ws + 4194304;            // 4 x 1048576 (Wq,Wk,Wv,Wo)
  unsigned short* Qd = ws + 8388608;            // [32][2048][64] (pre-scaled 1/8)
  unsigned short* Kd = ws + 12582912;           // [32][2048][64]
  unsigned short* Vt = ws + 16777216;           // [32][64][2048]
  unsigned short* Ob = ws + 20971520;           // [4096][1024]
  int* map = (int*)(ws + 25165824);             // [32][32]

  convert_all<<<8192, 256, 0, stream>>>(x, Wq, Wk, Wv, Wo, ws);
  mask_reduce<<<dim3(32, 32), 256, 0, stream>>>(mask, map);
  gemm_qkv<<<dim3(16, 32, 3), 128, 0, stream>>>(xb, wb, bq, bk, bv, Qd, Kd, Vt);
  flash_attn<<<dim3(16, 32), 512, 0, stream>>>(Qd, Kd, Vt, map, mask, Ob);
  gemm_out<<<dim3(16, 32), 128, 0, stream>>>(Ob, wb + 3 * 1048576, bo, out);
}

// Round 4
// 141.523 us; speedup vs baseline: 2.2200x; 1.1605x over previous
//
#include <hip/hip_runtime.h>
#include <stdint.h>
#include <stddef.h>

#define SEQ 2048
#define NH 16
#define HD 64
#define NB 2
#define HID 1024

typedef short bf16x8 __attribute__((ext_vector_type(8)));
typedef float f32x4 __attribute__((ext_vector_type(4)));
typedef float f32x16 __attribute__((ext_vector_type(16)));
typedef unsigned u32x2 __attribute__((ext_vector_type(2)));

__device__ __forceinline__ unsigned short f2bf(float f) {
  unsigned u = __float_as_uint(f);
  u += 0x7fffu + ((u >> 16) & 1u);
  return (unsigned short)(u >> 16);
}

__device__ __forceinline__ unsigned cvtpk(float lo, float hi) {
  unsigned d;
  asm("v_cvt_pk_bf16_f32 %0, %1, %2" : "=v"(d) : "v"(lo), "v"(hi));
  return d;
}

__device__ __forceinline__ void load_lds16(const void* g, void* l) {
  __builtin_amdgcn_global_load_lds(
      (const __attribute__((address_space(1))) unsigned int*)g,
      (__attribute__((address_space(3))) unsigned int*)l, 16, 0, 0);
}

// ---------------- fp32 -> bf16 conversion of x and the 4 weight matrices ----
__global__ __launch_bounds__(256) void convert_all(
    const float* __restrict__ x, const float* __restrict__ wq,
    const float* __restrict__ wk, const float* __restrict__ wv,
    const float* __restrict__ wo, unsigned short* __restrict__ dst) {
  long i = ((long)blockIdx.x * 256 + threadIdx.x) * 4;
  const float* src; long off;
  if (i < 4194304L)      { src = x;  off = i; }
  else if (i < 5242880L) { src = wq; off = i - 4194304L; }
  else if (i < 6291456L) { src = wk; off = i - 5242880L; }
  else if (i < 7340032L) { src = wv; off = i - 6291456L; }
  else                   { src = wo; off = i - 7340032L; }
  float4 v = *reinterpret_cast<const float4*>(src + off);
  ushort4 o;
  o.x = f2bf(v.x); o.y = f2bf(v.y); o.z = f2bf(v.z); o.w = f2bf(v.w);
  *reinterpret_cast<ushort4*>(dst + i) = o;
}

// ---------------- mask -> 64x64-block "any zero" map ------------------------
__global__ __launch_bounds__(256) void mask_reduce(const int* __restrict__ mask,
                                                   int* __restrict__ map) {
  const int qb = blockIdx.y, kb = blockIdx.x;
  int bad = 0;
  for (int i = threadIdx.x; i < 4096; i += 256) {
    int qq = i >> 6, kk = i & 63;
    bad |= (mask[(size_t)(qb * 64 + qq) * SEQ + kb * 64 + kk] == 0);
  }
  __shared__ int red[4];
  unsigned long long any = __ballot(bad);
  if ((threadIdx.x & 63) == 0) red[threadIdx.x >> 6] = (any != 0ULL);
  __syncthreads();
  if (threadIdx.x == 0) map[qb * 32 + kb] = red[0] | red[1] | red[2] | red[3];
}

// ---------------- shared GEMM main loop: C(128x64) = A * B^T ----------------
__device__ __forceinline__ void gemm_bt_core(
    const unsigned short* __restrict__ A, const unsigned short* __restrict__ Bw,
    int m0, int n0, unsigned short* As, unsigned short* Bs, f32x4 acc[4][4]) {
  const int t = threadIdx.x;
  const int lane = t & 63;
  const int wave = t >> 6;
  const int r = lane & 15;
  const int g = lane >> 4;
  for (int k0 = 0; k0 < HID; k0 += 32) {
#pragma unroll
    for (int i = 0; i < 4; ++i) {
      int chunk = i * 128 + t;
      load_lds16(A + (size_t)(m0 + (chunk >> 2)) * HID + k0 + ((chunk & 3) << 3),
                 As + chunk * 8);
    }
#pragma unroll
    for (int i = 0; i < 2; ++i) {
      int chunk = i * 128 + t;
      load_lds16(Bw + (size_t)(n0 + (chunk >> 2)) * HID + k0 + ((chunk & 3) << 3),
                 Bs + chunk * 8);
    }
    __syncthreads();
    bf16x8 af[4], bfr[4];
#pragma unroll
    for (int mt = 0; mt < 4; ++mt)
      af[mt] = *reinterpret_cast<const bf16x8*>(As + (wave * 64 + mt * 16 + r) * 32 + g * 8);
#pragma unroll
    for (int nt = 0; nt < 4; ++nt)
      bfr[nt] = *reinterpret_cast<const bf16x8*>(Bs + (nt * 16 + r) * 32 + g * 8);
#pragma unroll
    for (int mt = 0; mt < 4; ++mt)
#pragma unroll
      for (int nt = 0; nt < 4; ++nt)
        acc[mt][nt] = __builtin_amdgcn_mfma_f32_16x16x32_bf16(af[mt], bfr[nt], acc[mt][nt], 0, 0, 0);
    __syncthreads();
  }
}

// ---------------- QKV projection (z = 0/1/2 -> Q/K/V) -----------------------
// Q output is pre-scaled by 1/8 (folds the attention scale into the GEMM).
__global__ __launch_bounds__(128) void gemm_qkv(
    const unsigned short* __restrict__ xb, const unsigned short* __restrict__ wb,
    const float* __restrict__ bq, const float* __restrict__ bk,
    const float* __restrict__ bv, unsigned short* __restrict__ Qd,
    unsigned short* __restrict__ Kd, unsigned short* __restrict__ Vt) {
  __shared__ __align__(16) unsigned short As[128 * 32];
  __shared__ __align__(16) unsigned short Bs[64 * 32];
  const int z = blockIdx.z;
  const unsigned short* W = wb + (size_t)z * (HID * HID);
  const float* bias = (z == 0) ? bq : (z == 1) ? bk : bv;
  const float scl = (z == 0) ? 0.125f : 1.0f;
  const int m0 = blockIdx.y * 128, n0 = blockIdx.x * 64;
  f32x4 zv = {0.f, 0.f, 0.f, 0.f};
  f32x4 acc[4][4];
#pragma unroll
  for (int a = 0; a < 4; ++a)
#pragma unroll
    for (int c = 0; c < 4; ++c) acc[a][c] = zv;
  gemm_bt_core(xb, W, m0, n0, As, Bs, acc);
  const int lane = threadIdx.x & 63, wave = threadIdx.x >> 6;
  const int r = lane & 15, g = lane >> 4;
#pragma unroll
  for (int mt = 0; mt < 4; ++mt) {
#pragma unroll
    for (int nt = 0; nt < 4; ++nt) {
      int n = n0 + nt * 16 + r;
      float bb = bias[n];
      int h = n >> 6, d = n & 63;
#pragma unroll
      for (int i = 0; i < 4; ++i) {
        int m = m0 + wave * 64 + mt * 16 + g * 4 + i;
        int b = m >> 11, s = m & 2047;
        int bh = b * NH + h;
        unsigned short val = f2bf((acc[mt][nt][i] + bb) * scl);
        if (z == 0)      Qd[((size_t)bh * SEQ + s) * HD + d] = val;
        else if (z == 1) Kd[((size_t)bh * SEQ + s) * HD + d] = val;
        else             Vt[((size_t)bh * HD + d) * SEQ + s] = val;
      }
    }
  }
}

// ---------------- output projection: fp32 out + bias ------------------------
__global__ __launch_bounds__(128) void gemm_out(
    const unsigned short* __restrict__ Ob, const unsigned short* __restrict__ Wob,
    const float* __restrict__ bo, float* __restrict__ out) {
  __shared__ __align__(16) unsigned short As[128 * 32];
  __shared__ __align__(16) unsigned short Bs[64 * 32];
  const int m0 = blockIdx.y * 128, n0 = blockIdx.x * 64;
  f32x4 zv = {0.f, 0.f, 0.f, 0.f};
  f32x4 acc[4][4];
#pragma unroll
  for (int a = 0; a < 4; ++a)
#pragma unroll
    for (int c = 0; c < 4; ++c) acc[a][c] = zv;
  gemm_bt_core(Ob, Wob, m0, n0, As, Bs, acc);
  const int lane = threadIdx.x & 63, wave = threadIdx.x >> 6;
  const int r = lane & 15, g = lane >> 4;
#pragma unroll
  for (int mt = 0; mt < 4; ++mt) {
#pragma unroll
    for (int nt = 0; nt < 4; ++nt) {
      int n = n0 + nt * 16 + r;
      float bb = bo[n];
#pragma unroll
      for (int i = 0; i < 4; ++i) {
        int m = m0 + wave * 64 + mt * 16 + g * 4 + i;
        out[(size_t)m * HID + n] = acc[mt][nt][i] + bb;
      }
    }
  }
}

// ---------------- flash attention v4: swapped-QK, in-register softmax --------
// grid (S/128, BH), 256 threads = 4 waves; wave owns 32 queries.
// 32x32x16 MFMA. S^T = mfma(K_rows, Q): lane owns col q=lane&31; its 32 P
// values (16 + 16 via lane^32) are lane-local. Softmax fully in registers;
// P packed to bf16 via v_cvt_pk + permlane32_swap; PV swapped (O^T = V^T P^T).
// Row-sum via ones-A MFMA on packed P. K,V^T 64x64 LDS dbuf, XOR-swizzled.
__global__ __launch_bounds__(256, 2) void flash_attn(
    const unsigned short* __restrict__ Q, const unsigned short* __restrict__ K,
    const unsigned short* __restrict__ Vt, const int* __restrict__ map,
    const int* __restrict__ mask, unsigned short* __restrict__ O) {
  __shared__ __align__(16) unsigned short Ks[2][64][64];
  __shared__ __align__(16) unsigned short Vs[2][64][64];
  const int bh = blockIdx.y;
  const int t = threadIdx.x;
  const int lane = t & 63, wave = t >> 6;
  const int q = lane & 31, hi = lane >> 5;
  const int q0w = blockIdx.x * 128 + wave * 32;
  const unsigned short* Qb = Q + (size_t)bh * SEQ * HD;
  const unsigned short* Kb = K + (size_t)bh * SEQ * HD;
  const unsigned short* Vb = Vt + (size_t)bh * HD * SEQ;

  // Q as B-operand fragments: lane holds Q[q0w+q][dd*16 + hi*8 + j]
  bf16x8 qfr[4];
#pragma unroll
  for (int dd = 0; dd < 4; ++dd)
    qfr[dd] = *reinterpret_cast<const bf16x8*>(
        Qb + (size_t)(q0w + q) * HD + dd * 16 + hi * 8);

  bf16x8 onesf;
#pragma unroll
  for (int j = 0; j < 8; ++j) onesf[j] = (short)0x3F80;  // bf16 1.0

  f32x16 zv16 = {0.f};
  f32x16 oacc[2];
  oacc[0] = zv16; oacc[1] = zv16;
  float mrun = -1e30f, lrun = 0.f;

  // staging: 256 threads cover rows {srow, srow+32} x 8 16B-slots.
  const int srow = t >> 3;
  const int sslot = t & 7;

#define STAGE_K(kbase, buf) do {                                            \
    int c0 = sslot ^ (srow & 7);                                            \
    load_lds16(Kb + (size_t)((kbase) + srow) * HD + c0 * 8,                 \
               &Ks[buf][srow][sslot * 8]);                                  \
    load_lds16(Kb + (size_t)((kbase) + 32 + srow) * HD + c0 * 8,            \
               &Ks[buf][32 + srow][sslot * 8]);                             \
  } while (0)
#define STAGE_V(kbase, buf) do {                                            \
    int c0 = sslot ^ (srow & 7);                                            \
    load_lds16(Vb + (size_t)srow * SEQ + (kbase) + c0 * 8,                  \
               &Vs[buf][srow][sslot * 8]);                                  \
    load_lds16(Vb + (size_t)(32 + srow) * SEQ + (kbase) + c0 * 8,           \
               &Vs[buf][32 + srow][sslot * 8]);                             \
  } while (0)
// read a 16B fragment at (row, 16B-slot s) with the XOR swizzle
#define KFR(row, s) \
  (*reinterpret_cast<const bf16x8*>(&Ks[cur][row][(((s) ^ ((row) & 7)) << 3)]))
#define VFR(row, s) \
  (*reinterpret_cast<const bf16x8*>(&Vs[cur][row][(((s) ^ ((row) & 7)) << 3)]))

  STAGE_K(0, 0);
  STAGE_V(0, 0);
  asm volatile("s_waitcnt vmcnt(0)" ::: "memory");
  __syncthreads();
  int cur = 0;

  for (int kb = 0; kb < SEQ; kb += 64) {
    if (kb + 64 < SEQ) {
      STAGE_K(kb + 64, cur ^ 1);
      STAGE_V(kb + 64, cur ^ 1);
    }
    // ---- S^T = K_tile * Q : sacc[ks] covers k rows ks*32..+31, col q ----
    f32x16 sacc[2];
    sacc[0] = zv16; sacc[1] = zv16;
    __builtin_amdgcn_s_setprio(1);
#pragma unroll
    for (int ks = 0; ks < 2; ++ks) {
      int row = ks * 32 + q;
#pragma unroll
      for (int dd = 0; dd < 4; ++dd) {
        bf16x8 kf = KFR(row, dd * 2 + hi);
        sacc[ks] = __builtin_amdgcn_mfma_f32_32x32x16_bf16(kf, qfr[dd], sacc[ks], 0, 0, 0);
      }
    }
    __builtin_amdgcn_s_setprio(0);
    // ---- in-register softmax: lane holds P[k][q] for 32 k values ----
    float p[32];
#pragma unroll
    for (int ks = 0; ks < 2; ++ks)
#pragma unroll
      for (int rg = 0; rg < 16; ++rg) p[ks * 16 + rg] = sacc[ks][rg];
    if (map[(q0w >> 6) * 32 + (kb >> 6)]) {  // only if mask has zeros
#pragma unroll
      for (int ks = 0; ks < 2; ++ks)
#pragma unroll
        for (int rg = 0; rg < 16; ++rg) {
          int kl = ks * 32 + (rg & 3) + 8 * (rg >> 2) + 4 * hi;
          if (mask[(size_t)(q0w + q) * SEQ + kb + kl] == 0)
            p[ks * 16 + rg] = -__builtin_inff();
        }
    }
    float pmax = p[0];
#pragma unroll
    for (int j = 1; j < 32; ++j) pmax = fmaxf(pmax, p[j]);
    pmax = fmaxf(pmax, __shfl_xor(pmax, 32, 64));
    // defer-max: rescale only when tile max beats running max by > 8
    if (!__all(pmax <= mrun + 8.0f)) {
      float mnew = fmaxf(mrun, pmax);
      float corr = __expf(mrun - mnew);
      mrun = mnew;
      lrun *= corr;
#pragma unroll
      for (int dh = 0; dh < 2; ++dh)
#pragma unroll
        for (int rg = 0; rg < 16; ++rg) oacc[dh][rg] *= corr;
    }
#pragma unroll
    for (int j = 0; j < 32; ++j) p[j] = __expf(p[j] - mrun);
    // ---- pack P to bf16 B-fragments via cvt_pk + permlane32_swap ----
    bf16x8 pfrag[4];
#pragma unroll
    for (int f = 0; f < 4; ++f) {  // f = ks*2 + half
      int b0 = f * 8;
      unsigned w0 = cvtpk(p[b0 + 0], p[b0 + 1]);
      unsigned w1 = cvtpk(p[b0 + 2], p[b0 + 3]);
      unsigned w2 = cvtpk(p[b0 + 4], p[b0 + 5]);
      unsigned w3 = cvtpk(p[b0 + 6], p[b0 + 7]);
      u32x2 s02 = __builtin_amdgcn_permlane32_swap(w0, w2, false, false);
      u32x2 s13 = __builtin_amdgcn_permlane32_swap(w1, w3, false, false);
      union { unsigned u[4]; bf16x8 v; } fr;
      fr.u[0] = s02[0]; fr.u[1] = s13[0]; fr.u[2] = s02[1]; fr.u[3] = s13[1];
      pfrag[f] = fr.v;
    }
    // ---- PV (O^T = V^T * P^T) + row-sum via ones-A MFMA ----
    f32x16 lacc = zv16;
    __builtin_amdgcn_s_setprio(1);
#pragma unroll
    for (int f = 0; f < 4; ++f)
      lacc = __builtin_amdgcn_mfma_f32_32x32x16_bf16(onesf, pfrag[f], lacc, 0, 0, 0);
#pragma unroll
    for (int dh = 0; dh < 2; ++dh) {
      int row = dh * 32 + q;
#pragma unroll
      for (int f = 0; f < 4; ++f) {
        bf16x8 vf = VFR(row, f * 2 + hi);
        oacc[dh] = __builtin_amdgcn_mfma_f32_32x32x16_bf16(vf, pfrag[f], oacc[dh], 0, 0, 0);
      }
    }
    __builtin_amdgcn_s_setprio(0);
    lrun += lacc[0];
    // next tile must be fully landed before we flip buffers
    asm volatile("s_waitcnt vmcnt(0)" ::: "memory");
    __syncthreads();
    cur ^= 1;
  }

  const float rl = 1.0f / lrun;
  const int b = bh >> 4, h = bh & 15;
  unsigned short* orow = O + (size_t)(b * SEQ + q0w + q) * HID + h * HD;
#pragma unroll
  for (int dh = 0; dh < 2; ++dh)
#pragma unroll
    for (int r2 = 0; r2 < 4; ++r2) {
      float v0 = oacc[dh][r2 * 4 + 0] * rl;
      float v1 = oacc[dh][r2 * 4 + 1] * rl;
      float v2 = oacc[dh][r2 * 4 + 2] * rl;
      float v3 = oacc[dh][r2 * 4 + 3] * rl;
      u32x2 pk;
      pk[0] = (unsigned)f2bf(v0) | ((unsigned)f2bf(v1) << 16);
      pk[1] = (unsigned)f2bf(v2) | ((unsigned)f2bf(v3) << 16);
      *reinterpret_cast<u32x2*>(orow + dh * 32 + r2 * 8 + hi * 4) = pk;
    }
#undef STAGE_K
#undef STAGE_V
#undef KFR
#undef VFR
}

// ---------------- launch -----------------------------------------------------
extern "C" void kernel_launch(void* const* d_in, const int* in_sizes, int n_in,
                              void* d_out, int out_size, void* d_ws, size_t ws_size,
                              hipStream_t stream) {
  const float* x    = (const float*)d_in[0];
  const int*   mask = (const int*)d_in[1];
  const float* Wq   = (const float*)d_in[2];
  const float* bq   = (const float*)d_in[3];
  const float* Wk   = (const float*)d_in[4];
  const float* bk   = (const float*)d_in[5];
  const float* Wv   = (const float*)d_in[6];
  const float* bv   = (const float*)d_in[7];
  const float* Wo   = (const float*)d_in[8];
  const float* bo   = (const float*)d_in[9];
  float* out = (float*)d_out;

  unsigned short* ws = (unsigned short*)d_ws;
  unsigned short* xb = ws;                      // 4194304 bf16
  unsigned short* wb = ws + 4194304;            // 4 x 1048576 (Wq,Wk,Wv,Wo)
  unsigned short* Qd = ws + 8388608;            // [32][2048][64] (pre-scaled 1/8)
  unsigned short* Kd = ws + 12582912;           // [32][2048][64]
  unsigned short* Vt = ws + 16777216;           // [32][64][2048]
  unsigned short* Ob = ws + 20971520;           // [4096][1024]
  int* map = (int*)(ws + 25165824);             // [32][32]

  convert_all<<<8192, 256, 0, stream>>>(x, Wq, Wk, Wv, Wo, ws);
  mask_reduce<<<dim3(32, 32), 256, 0, stream>>>(mask, map);
  gemm_qkv<<<dim3(16, 32, 3), 128, 0, stream>>>(xb, wb, bq, bk, bv, Qd, Kd, Vt);
  flash_attn<<<dim3(16, 32), 256, 0, stream>>>(Qd, Kd, Vt, map, mask, Ob);
  gemm_out<<<dim3(16, 32), 128, 0, stream>>>(Ob, wb + 3 * 1048576, bo, out);
}

// Round 5
// 136.250 us; speedup vs baseline: 2.3059x; 1.0387x over previous
//
#include <hip/hip_runtime.h>
#include <stdint.h>
#include <stddef.h>

#define SEQ 2048
#define NH 16
#define HD 64
#define NB 2
#define HID 1024

typedef short bf16x8 __attribute__((ext_vector_type(8)));
typedef float f32x4 __attribute__((ext_vector_type(4)));
typedef float f32x16 __attribute__((ext_vector_type(16)));
typedef unsigned u32x2 __attribute__((ext_vector_type(2)));

__device__ __forceinline__ unsigned short f2bf(float f) {
  unsigned u = __float_as_uint(f);
  u += 0x7fffu + ((u >> 16) & 1u);
  return (unsigned short)(u >> 16);
}

__device__ __forceinline__ unsigned cvtpk(float lo, float hi) {
  unsigned d;
  asm("v_cvt_pk_bf16_f32 %0, %1, %2" : "=v"(d) : "v"(lo), "v"(hi));
  return d;
}

__device__ __forceinline__ void load_lds16(const void* g, void* l) {
  __builtin_amdgcn_global_load_lds(
      (const __attribute__((address_space(1))) unsigned int*)g,
      (__attribute__((address_space(3))) unsigned int*)l, 16, 0, 0);
}

// ---------------- fp32 -> bf16 conversion of x and the 4 weight matrices ----
__global__ __launch_bounds__(256) void convert_all(
    const float* __restrict__ x, const float* __restrict__ wq,
    const float* __restrict__ wk, const float* __restrict__ wv,
    const float* __restrict__ wo, unsigned short* __restrict__ dst) {
  long i = ((long)blockIdx.x * 256 + threadIdx.x) * 4;
  const float* src; long off;
  if (i < 4194304L)      { src = x;  off = i; }
  else if (i < 5242880L) { src = wq; off = i - 4194304L; }
  else if (i < 6291456L) { src = wk; off = i - 5242880L; }
  else if (i < 7340032L) { src = wv; off = i - 6291456L; }
  else                   { src = wo; off = i - 7340032L; }
  float4 v = *reinterpret_cast<const float4*>(src + off);
  ushort4 o;
  o.x = f2bf(v.x); o.y = f2bf(v.y); o.z = f2bf(v.z); o.w = f2bf(v.w);
  *reinterpret_cast<ushort4*>(dst + i) = o;
}

// ---------------- mask -> 64x64-block "any zero" map ------------------------
__global__ __launch_bounds__(256) void mask_reduce(const int* __restrict__ mask,
                                                   int* __restrict__ map) {
  const int qb = blockIdx.y, kb = blockIdx.x;
  int bad = 0;
  for (int i = threadIdx.x; i < 4096; i += 256) {
    int qq = i >> 6, kk = i & 63;
    bad |= (mask[(size_t)(qb * 64 + qq) * SEQ + kb * 64 + kk] == 0);
  }
  __shared__ int red[4];
  unsigned long long any = __ballot(bad);
  if ((threadIdx.x & 63) == 0) red[threadIdx.x >> 6] = (any != 0ULL);
  __syncthreads();
  if (threadIdx.x == 0) map[qb * 32 + kb] = red[0] | red[1] | red[2] | red[3];
}

// ---------------- m97-structure GEMM core: C(128x128) = A * B^T --------------
// 256 threads = 4 waves (2x2); wave owns 64x64 = 4x4 MFMA 16x16x32 frags.
// A: MxK row-major bf16 (K=HID), Bw: NxK row-major bf16. BK=32, 2 barriers/step.
__device__ __forceinline__ void gemm128_core(
    const unsigned short* __restrict__ A, const unsigned short* __restrict__ Bw,
    int m0, int n0, unsigned short* As, unsigned short* Bs, f32x4 acc[4][4]) {
  const int t = threadIdx.x;
  const int lane = t & 63;
  const int r = lane & 15, g = lane >> 4;
  const int wr = (t >> 6) >> 1, wc = (t >> 6) & 1;
  for (int k0 = 0; k0 < HID; k0 += 32) {
#pragma unroll
    for (int i = 0; i < 2; ++i) {
      int c = i * 256 + t;           // 512 16B-chunks per 128x32 tile
      int row = c >> 2, sl = (c & 3) << 3;
      load_lds16(A + (size_t)(m0 + row) * HID + k0 + sl, As + c * 8);
      load_lds16(Bw + (size_t)(n0 + row) * HID + k0 + sl, Bs + c * 8);
    }
    __syncthreads();
    bf16x8 af[4], bf[4];
#pragma unroll
    for (int mt = 0; mt < 4; ++mt)
      af[mt] = *reinterpret_cast<const bf16x8*>(As + (wr * 64 + mt * 16 + r) * 32 + g * 8);
#pragma unroll
    for (int nt = 0; nt < 4; ++nt)
      bf[nt] = *reinterpret_cast<const bf16x8*>(Bs + (wc * 64 + nt * 16 + r) * 32 + g * 8);
#pragma unroll
    for (int mt = 0; mt < 4; ++mt)
#pragma unroll
      for (int nt = 0; nt < 4; ++nt)
        acc[mt][nt] = __builtin_amdgcn_mfma_f32_16x16x32_bf16(af[mt], bf[nt], acc[mt][nt], 0, 0, 0);
    __syncthreads();
  }
}

// ---------------- fused QKV projection (N = 3072, z = n>>10) -----------------
// Q output pre-scaled by 1/8. Wq,Wk,Wv contiguous in wb -> one 3072x1024 B.
__global__ __launch_bounds__(256) void gemm_qkv(
    const unsigned short* __restrict__ xb, const unsigned short* __restrict__ wb,
    const float* __restrict__ bq, const float* __restrict__ bk,
    const float* __restrict__ bv, unsigned short* __restrict__ Qd,
    unsigned short* __restrict__ Kd, unsigned short* __restrict__ Vt) {
  __shared__ __align__(16) unsigned short As[128 * 32];
  __shared__ __align__(16) unsigned short Bs[128 * 32];
  const int m0 = blockIdx.y * 128, n0 = blockIdx.x * 128;
  const int z = n0 >> 10;  // 128-tile never straddles a weight boundary
  f32x4 zv = {0.f, 0.f, 0.f, 0.f};
  f32x4 acc[4][4];
#pragma unroll
  for (int a = 0; a < 4; ++a)
#pragma unroll
    for (int c = 0; c < 4; ++c) acc[a][c] = zv;
  gemm128_core(xb, wb, m0, n0, As, Bs, acc);
  const int t = threadIdx.x, lane = t & 63;
  const int r = lane & 15, g = lane >> 4;
  const int wr = (t >> 6) >> 1, wc = (t >> 6) & 1;
  const float* bias = (z == 0) ? bq : (z == 1) ? bk : bv;
  const float scl = (z == 0) ? 0.125f : 1.0f;
#pragma unroll
  for (int nt = 0; nt < 4; ++nt) {
    int n = n0 + wc * 64 + nt * 16 + r;
    int nn = n & 1023;
    float bb = bias[nn];
    int h = nn >> 6, d = nn & 63;
#pragma unroll
    for (int mt = 0; mt < 4; ++mt) {
#pragma unroll
      for (int i = 0; i < 4; ++i) {
        int m = m0 + wr * 64 + mt * 16 + g * 4 + i;
        int b = m >> 11, s = m & 2047;
        int bh = b * NH + h;
        unsigned short val = f2bf((acc[mt][nt][i] + bb) * scl);
        if (z == 0)      Qd[((size_t)bh * SEQ + s) * HD + d] = val;
        else if (z == 1) Kd[((size_t)bh * SEQ + s) * HD + d] = val;
        else             Vt[((size_t)bh * HD + d) * SEQ + s] = val;
      }
    }
  }
}

// ---------------- output projection: fp32 out + bias ------------------------
__global__ __launch_bounds__(256) void gemm_out(
    const unsigned short* __restrict__ Ob, const unsigned short* __restrict__ Wob,
    const float* __restrict__ bo, float* __restrict__ out) {
  __shared__ __align__(16) unsigned short As[128 * 32];
  __shared__ __align__(16) unsigned short Bs[128 * 32];
  const int m0 = blockIdx.y * 128, n0 = blockIdx.x * 128;
  f32x4 zv = {0.f, 0.f, 0.f, 0.f};
  f32x4 acc[4][4];
#pragma unroll
  for (int a = 0; a < 4; ++a)
#pragma unroll
    for (int c = 0; c < 4; ++c) acc[a][c] = zv;
  gemm128_core(Ob, Wob, m0, n0, As, Bs, acc);
  const int t = threadIdx.x, lane = t & 63;
  const int r = lane & 15, g = lane >> 4;
  const int wr = (t >> 6) >> 1, wc = (t >> 6) & 1;
#pragma unroll
  for (int nt = 0; nt < 4; ++nt) {
    int n = n0 + wc * 64 + nt * 16 + r;
    float bb = bo[n];
#pragma unroll
    for (int mt = 0; mt < 4; ++mt) {
#pragma unroll
      for (int i = 0; i < 4; ++i) {
        int m = m0 + wr * 64 + mt * 16 + g * 4 + i;
        out[(size_t)m * HID + n] = acc[mt][nt][i] + bb;
      }
    }
  }
}

// ---------------- flash attention v4: swapped-QK, in-register softmax --------
// grid (S/128, BH), 256 threads = 4 waves; wave owns 32 queries.
// 32x32x16 MFMA. S^T = mfma(K_rows, Q): lane owns col q=lane&31; its 32 P
// values (16 + 16 via lane^32) are lane-local. Softmax fully in registers;
// P packed to bf16 via v_cvt_pk + permlane32_swap; PV swapped (O^T = V^T P^T).
// Row-sum via ones-A MFMA on packed P. K,V^T 64x64 LDS dbuf, XOR-swizzled.
__global__ __launch_bounds__(256, 2) void flash_attn(
    const unsigned short* __restrict__ Q, const unsigned short* __restrict__ K,
    const unsigned short* __restrict__ Vt, const int* __restrict__ map,
    const int* __restrict__ mask, unsigned short* __restrict__ O) {
  __shared__ __align__(16) unsigned short Ks[2][64][64];
  __shared__ __align__(16) unsigned short Vs[2][64][64];
  const int bh = blockIdx.y;
  const int t = threadIdx.x;
  const int lane = t & 63, wave = t >> 6;
  const int q = lane & 31, hi = lane >> 5;
  const int q0w = blockIdx.x * 128 + wave * 32;
  const unsigned short* Qb = Q + (size_t)bh * SEQ * HD;
  const unsigned short* Kb = K + (size_t)bh * SEQ * HD;
  const unsigned short* Vb = Vt + (size_t)bh * HD * SEQ;

  // Q as B-operand fragments: lane holds Q[q0w+q][dd*16 + hi*8 + j]
  bf16x8 qfr[4];
#pragma unroll
  for (int dd = 0; dd < 4; ++dd)
    qfr[dd] = *reinterpret_cast<const bf16x8*>(
        Qb + (size_t)(q0w + q) * HD + dd * 16 + hi * 8);

  bf16x8 onesf;
#pragma unroll
  for (int j = 0; j < 8; ++j) onesf[j] = (short)0x3F80;  // bf16 1.0

  f32x16 zv16 = {0.f};
  f32x16 oacc[2];
  oacc[0] = zv16; oacc[1] = zv16;
  float mrun = -1e30f, lrun = 0.f;

  // staging: 256 threads cover rows {srow, srow+32} x 8 16B-slots.
  const int srow = t >> 3;
  const int sslot = t & 7;

#define STAGE_K(kbase, buf) do {                                            \
    int c0 = sslot ^ (srow & 7);                                            \
    load_lds16(Kb + (size_t)((kbase) + srow) * HD + c0 * 8,                 \
               &Ks[buf][srow][sslot * 8]);                                  \
    load_lds16(Kb + (size_t)((kbase) + 32 + srow) * HD + c0 * 8,            \
               &Ks[buf][32 + srow][sslot * 8]);                             \
  } while (0)
#define STAGE_V(kbase, buf) do {                                            \
    int c0 = sslot ^ (srow & 7);                                            \
    load_lds16(Vb + (size_t)srow * SEQ + (kbase) + c0 * 8,                  \
               &Vs[buf][srow][sslot * 8]);                                  \
    load_lds16(Vb + (size_t)(32 + srow) * SEQ + (kbase) + c0 * 8,           \
               &Vs[buf][32 + srow][sslot * 8]);                             \
  } while (0)
// read a 16B fragment at (row, 16B-slot s) with the XOR swizzle
#define KFR(row, s) \
  (*reinterpret_cast<const bf16x8*>(&Ks[cur][row][(((s) ^ ((row) & 7)) << 3)]))
#define VFR(row, s) \
  (*reinterpret_cast<const bf16x8*>(&Vs[cur][row][(((s) ^ ((row) & 7)) << 3)]))

  STAGE_K(0, 0);
  STAGE_V(0, 0);
  asm volatile("s_waitcnt vmcnt(0)" ::: "memory");
  __syncthreads();
  int cur = 0;

  for (int kb = 0; kb < SEQ; kb += 64) {
    if (kb + 64 < SEQ) {
      STAGE_K(kb + 64, cur ^ 1);
      STAGE_V(kb + 64, cur ^ 1);
    }
    // ---- S^T = K_tile * Q : sacc[ks] covers k rows ks*32..+31, col q ----
    f32x16 sacc[2];
    sacc[0] = zv16; sacc[1] = zv16;
    __builtin_amdgcn_s_setprio(1);
#pragma unroll
    for (int ks = 0; ks < 2; ++ks) {
      int row = ks * 32 + q;
#pragma unroll
      for (int dd = 0; dd < 4; ++dd) {
        bf16x8 kf = KFR(row, dd * 2 + hi);
        sacc[ks] = __builtin_amdgcn_mfma_f32_32x32x16_bf16(kf, qfr[dd], sacc[ks], 0, 0, 0);
      }
    }
    __builtin_amdgcn_s_setprio(0);
    // ---- in-register softmax: lane holds P[k][q] for 32 k values ----
    float p[32];
#pragma unroll
    for (int ks = 0; ks < 2; ++ks)
#pragma unroll
      for (int rg = 0; rg < 16; ++rg) p[ks * 16 + rg] = sacc[ks][rg];
    if (map[(q0w >> 6) * 32 + (kb >> 6)]) {  // only if mask has zeros
#pragma unroll
      for (int ks = 0; ks < 2; ++ks)
#pragma unroll
        for (int rg = 0; rg < 16; ++rg) {
          int kl = ks * 32 + (rg & 3) + 8 * (rg >> 2) + 4 * hi;
          if (mask[(size_t)(q0w + q) * SEQ + kb + kl] == 0)
            p[ks * 16 + rg] = -__builtin_inff();
        }
    }
    float pmax = p[0];
#pragma unroll
    for (int j = 1; j < 32; ++j) pmax = fmaxf(pmax, p[j]);
    pmax = fmaxf(pmax, __shfl_xor(pmax, 32, 64));
    // defer-max: rescale only when tile max beats running max by > 8
    if (!__all(pmax <= mrun + 8.0f)) {
      float mnew = fmaxf(mrun, pmax);
      float corr = __expf(mrun - mnew);
      mrun = mnew;
      lrun *= corr;
#pragma unroll
      for (int dh = 0; dh < 2; ++dh)
#pragma unroll
        for (int rg = 0; rg < 16; ++rg) oacc[dh][rg] *= corr;
    }
#pragma unroll
    for (int j = 0; j < 32; ++j) p[j] = __expf(p[j] - mrun);
    // ---- pack P to bf16 B-fragments via cvt_pk + permlane32_swap ----
    bf16x8 pfrag[4];
#pragma unroll
    for (int f = 0; f < 4; ++f) {  // f = ks*2 + half
      int b0 = f * 8;
      unsigned w0 = cvtpk(p[b0 + 0], p[b0 + 1]);
      unsigned w1 = cvtpk(p[b0 + 2], p[b0 + 3]);
      unsigned w2 = cvtpk(p[b0 + 4], p[b0 + 5]);
      unsigned w3 = cvtpk(p[b0 + 6], p[b0 + 7]);
      u32x2 s02 = __builtin_amdgcn_permlane32_swap(w0, w2, false, false);
      u32x2 s13 = __builtin_amdgcn_permlane32_swap(w1, w3, false, false);
      union { unsigned u[4]; bf16x8 v; } fr;
      fr.u[0] = s02[0]; fr.u[1] = s13[0]; fr.u[2] = s02[1]; fr.u[3] = s13[1];
      pfrag[f] = fr.v;
    }
    // ---- PV (O^T = V^T * P^T) + row-sum via ones-A MFMA ----
    f32x16 lacc = zv16;
    __builtin_amdgcn_s_setprio(1);
#pragma unroll
    for (int f = 0; f < 4; ++f)
      lacc = __builtin_amdgcn_mfma_f32_32x32x16_bf16(onesf, pfrag[f], lacc, 0, 0, 0);
#pragma unroll
    for (int dh = 0; dh < 2; ++dh) {
      int row = dh * 32 + q;
#pragma unroll
      for (int f = 0; f < 4; ++f) {
        bf16x8 vf = VFR(row, f * 2 + hi);
        oacc[dh] = __builtin_amdgcn_mfma_f32_32x32x16_bf16(vf, pfrag[f], oacc[dh], 0, 0, 0);
      }
    }
    __builtin_amdgcn_s_setprio(0);
    lrun += lacc[0];
    // next tile must be fully landed before we flip buffers
    asm volatile("s_waitcnt vmcnt(0)" ::: "memory");
    __syncthreads();
    cur ^= 1;
  }

  const float rl = 1.0f / lrun;
  const int b = bh >> 4, h = bh & 15;
  unsigned short* orow = O + (size_t)(b * SEQ + q0w + q) * HID + h * HD;
#pragma unroll
  for (int dh = 0; dh < 2; ++dh)
#pragma unroll
    for (int r2 = 0; r2 < 4; ++r2) {
      float v0 = oacc[dh][r2 * 4 + 0] * rl;
      float v1 = oacc[dh][r2 * 4 + 1] * rl;
      float v2 = oacc[dh][r2 * 4 + 2] * rl;
      float v3 = oacc[dh][r2 * 4 + 3] * rl;
      u32x2 pk;
      pk[0] = (unsigned)f2bf(v0) | ((unsigned)f2bf(v1) << 16);
      pk[1] = (unsigned)f2bf(v2) | ((unsigned)f2bf(v3) << 16);
      *reinterpret_cast<u32x2*>(orow + dh * 32 + r2 * 8 + hi * 4) = pk;
    }
#undef STAGE_K
#undef STAGE_V
#undef KFR
#undef VFR
}

// ---------------- launch -----------------------------------------------------
extern "C" void kernel_launch(void* const* d_in, const int* in_sizes, int n_in,
                              void* d_out, int out_size, void* d_ws, size_t ws_size,
                              hipStream_t stream) {
  const float* x    = (const float*)d_in[0];
  const int*   mask = (const int*)d_in[1];
  const float* Wq   = (const float*)d_in[2];
  const float* bq   = (const float*)d_in[3];
  const float* Wk   = (const float*)d_in[4];
  const float* bk   = (const float*)d_in[5];
  const float* Wv   = (const float*)d_in[6];
  const float* bv   = (const float*)d_in[7];
  const float* Wo   = (const float*)d_in[8];
  const float* bo   = (const float*)d_in[9];
  float* out = (float*)d_out;

  unsigned short* ws = (unsigned short*)d_ws;
  unsigned short* xb = ws;                      // 4194304 bf16
  unsigned short* wb = ws + 4194304;            // 4 x 1048576 (Wq,Wk,Wv,Wo)
  unsigned short* Qd = ws + 8388608;            // [32][2048][64] (pre-scaled 1/8)
  unsigned short* Kd = ws + 12582912;           // [32][2048][64]
  unsigned short* Vt = ws + 16777216;           // [32][64][2048]
  unsigned short* Ob = ws + 20971520;           // [4096][1024]
  int* map = (int*)(ws + 25165824);             // [32][32]

  convert_all<<<8192, 256, 0, stream>>>(x, Wq, Wk, Wv, Wo, ws);
  mask_reduce<<<dim3(32, 32), 256, 0, stream>>>(mask, map);
  gemm_qkv<<<dim3(24, 32), 256, 0, stream>>>(xb, wb, bq, bk, bv, Qd, Kd, Vt);
  flash_attn<<<dim3(16, 32), 256, 0, stream>>>(Qd, Kd, Vt, map, mask, Ob);
  gemm_out<<<dim3(8, 32), 256, 0, stream>>>(Ob, wb + 3 * 1048576, bo, out);
}